// Round 5
// baseline (897.938 us; speedup 1.0000x reference)
//
#include <hip/hip_runtime.h>

typedef __bf16 bf16;
typedef bf16 bf16x8 __attribute__((ext_vector_type(8)));
typedef float f32x4 __attribute__((ext_vector_type(4)));

#define LD64  80   // padded LDS row stride (elems) for 64-wide tiles
#define LD128 144  // padded LDS row stride for 128-wide tiles

static __device__ __forceinline__ f32x4 mfma16(bf16x8 a, bf16x8 b, f32x4 c) {
    return __builtin_amdgcn_mfma_f32_16x16x32_bf16(a, b, c, 0, 0, 0);
}

// ---------------------------------------------------------------------------
// convert: emb fp32 -> bf16 (tier A+ only)
// ---------------------------------------------------------------------------
__global__ __launch_bounds__(256) void convert_kernel(
    const float* __restrict__ src, bf16* __restrict__ dst, int n8)
{
    int i = blockIdx.x * 256 + threadIdx.x;
    const int stride = gridDim.x * 256;
    for (; i < n8; i += stride) {
        const float4* s = (const float4*)(src + (size_t)i * 8);
        float4 a = s[0], b = s[1];
        bf16x8 v = {(bf16)a.x, (bf16)a.y, (bf16)a.z, (bf16)a.w,
                    (bf16)b.x, (bf16)b.y, (bf16)b.z, (bf16)b.w};
        *(bf16x8*)(dst + (size_t)i * 8) = v;
    }
}

// ---------------------------------------------------------------------------
// hist2: cnt1 = histogram of rel1 dests; cnt2 = histogram of rel2 arg-slot dests
// ---------------------------------------------------------------------------
__global__ __launch_bounds__(256) void hist2_kernel(
    const int* __restrict__ idx1, const int* __restrict__ idx2,
    int* __restrict__ cnt1, int* __restrict__ cnt2, int M1, int total)
{
    int s = blockIdx.x * 256 + threadIdx.x;
    const int stride = gridDim.x * 256;
    for (; s < total; s += stride) {
        if (s < M1) atomicAdd(&cnt1[idx1[s]], 1);
        else        atomicAdd(&cnt2[idx2[s - M1]], 1);
    }
}

// ---------------------------------------------------------------------------
// scan: exclusive prefix sum of cnt[0..N) -> pos. Single block, 1024 threads.
// ---------------------------------------------------------------------------
#define SCAN_T 1024
__global__ __launch_bounds__(SCAN_T) void scan_kernel(
    const int* __restrict__ cnt, int* __restrict__ pos, int N)
{
    __shared__ int sSum[SCAN_T];
    const int t = threadIdx.x;
    const int chunk = (N + SCAN_T - 1) / SCAN_T;
    const int base = t * chunk;
    int s = 0;
    for (int i = 0; i < chunk; ++i) {
        int ix = base + i;
        if (ix < N) s += cnt[ix];
    }
    sSum[t] = s;
    __syncthreads();
    for (int off = 1; off < SCAN_T; off <<= 1) {
        int v = (t >= off) ? sSum[t - off] : 0;
        __syncthreads();
        sSum[t] += v;
        __syncthreads();
    }
    int excl = (t == 0) ? 0 : sSum[t - 1];
    for (int i = 0; i < chunk; ++i) {
        int ix = base + i;
        if (ix < N) {
            pos[ix] = excl;
            excl += cnt[ix];
        }
    }
}

// ---------------------------------------------------------------------------
// fill: dest-sorted arg-slot list for rel2 via per-node atomic cursors.
// slot s in [0, 2*M2): dest = idx2[s].
// ---------------------------------------------------------------------------
__global__ __launch_bounds__(256) void fill_kernel(
    const int* __restrict__ idx2, int* __restrict__ pos,
    int* __restrict__ list, int S)
{
    int s = blockIdx.x * 256 + threadIdx.x;
    const int stride = gridDim.x * 256;
    for (; s < S; s += stride) {
        int p = atomicAdd(&pos[idx2[s]], 1);
        list[p] = s;
    }
}

// ---------------------------------------------------------------------------
// rel1_dense: agg[n] = cnt1[n] * MLP1(emb[n]). Dense, plain stores, no
// atomics, no memset needed (writes every row). Duplicate unary atoms have
// identical messages, so count*message == segment_sum.
// ---------------------------------------------------------------------------
__global__ __launch_bounds__(256) void rel1_dense_kernel(
    const float* __restrict__ emb, const int* __restrict__ cnt,
    const float* __restrict__ W1, const float* __restrict__ b1,
    const float* __restrict__ W2, const float* __restrict__ b2,
    float* __restrict__ agg, int N, int numTiles)
{
    __shared__ bf16 sW1t[64 * LD64];   // [n][k]
    __shared__ bf16 sW2t[64 * LD64];
    __shared__ bf16 sG[64 * LD64];
    __shared__ bf16 sH[64 * LD64];
    __shared__ float sB1[64], sB2[64];

    const int t = threadIdx.x;
    const int wave = t >> 6, lane = t & 63;
    const int l15 = lane & 15, quad = lane >> 4;

    for (int i = t; i < 64 * 64; i += 256) {
        int k = i >> 6, n = i & 63;
        sW1t[n * LD64 + k] = (bf16)W1[i];
        sW2t[n * LD64 + k] = (bf16)W2[i];
    }
    if (t < 64) { sB1[t] = b1[t]; sB2[t] = b2[t]; }

    for (int tile = blockIdx.x; tile < numTiles; tile += gridDim.x) {
        __syncthreads();
        const int base = tile * 64;
        {   // dense load: 4 threads per row, 16 floats each
            const int r = t >> 2, p = t & 3;
            const int R = base + r;
            if (R < N) {
                const float4* src = (const float4*)(emb + (size_t)R * 64 + p * 16);
                #pragma unroll
                for (int i = 0; i < 4; ++i) {
                    float4 v = src[i];
                    int c = p * 16 + i * 4;
                    sG[r * LD64 + c + 0] = (bf16)v.x;
                    sG[r * LD64 + c + 1] = (bf16)v.y;
                    sG[r * LD64 + c + 2] = (bf16)v.z;
                    sG[r * LD64 + c + 3] = (bf16)v.w;
                }
            }
        }
        __syncthreads();

        f32x4 acc[4];
        #pragma unroll
        for (int nt = 0; nt < 4; ++nt) acc[nt] = (f32x4){0.f, 0.f, 0.f, 0.f};
        #pragma unroll
        for (int kt = 0; kt < 2; ++kt) {
            bf16x8 a = *(const bf16x8*)&sG[(wave * 16 + l15) * LD64 + kt * 32 + quad * 8];
            #pragma unroll
            for (int nt = 0; nt < 4; ++nt) {
                bf16x8 bf = *(const bf16x8*)&sW1t[(nt * 16 + l15) * LD64 + kt * 32 + quad * 8];
                acc[nt] = mfma16(a, bf, acc[nt]);
            }
        }
        #pragma unroll
        for (int nt = 0; nt < 4; ++nt) {
            float bias = sB1[nt * 16 + l15];
            #pragma unroll
            for (int r = 0; r < 4; ++r) {
                float v = acc[nt][r] + bias;
                v = v > 0.f ? v : 0.f;
                sH[(wave * 16 + quad * 4 + r) * LD64 + nt * 16 + l15] = (bf16)v;
            }
        }
        __syncthreads();

        f32x4 acc2[4];
        #pragma unroll
        for (int nt = 0; nt < 4; ++nt) acc2[nt] = (f32x4){0.f, 0.f, 0.f, 0.f};
        #pragma unroll
        for (int kt = 0; kt < 2; ++kt) {
            bf16x8 a = *(const bf16x8*)&sH[(wave * 16 + l15) * LD64 + kt * 32 + quad * 8];
            #pragma unroll
            for (int nt = 0; nt < 4; ++nt) {
                bf16x8 bf = *(const bf16x8*)&sW2t[(nt * 16 + l15) * LD64 + kt * 32 + quad * 8];
                acc2[nt] = mfma16(a, bf, acc2[nt]);
            }
        }
        #pragma unroll
        for (int nt = 0; nt < 4; ++nt) {
            float bias = sB2[nt * 16 + l15];
            #pragma unroll
            for (int r = 0; r < 4; ++r) {
                int row = wave * 16 + quad * 4 + r;
                int R = base + row;
                if (R < N) {
                    float scale = (float)cnt[R];
                    agg[(size_t)R * 64 + nt * 16 + l15] = scale * (acc2[nt][r] + bias);
                }
            }
        }
    }
}

// ---------------------------------------------------------------------------
// rel2_sorted: process dest-sorted arg-slots. slot = 2*edge+arg; compute full
// 128-wide MLP for the edge, scatter only this arg's 64-col slice. Runs of
// equal dest are reduced in-register (wave-uniform boundaries: wave == row
// group) before atomicAdd -> ~10x fewer atomics.
// ---------------------------------------------------------------------------
template<bool BF16EMB>
__global__ __launch_bounds__(256) void rel2_sorted_kernel(
    const float* __restrict__ emb, const bf16* __restrict__ embb,
    const int* __restrict__ idx,  // [2*M] flat
    const float* __restrict__ W1, const float* __restrict__ b1,  // 128x128, 128
    const float* __restrict__ W2, const float* __restrict__ b2,
    const int* __restrict__ list, float* __restrict__ agg,
    int S, int numTiles)
{
    __shared__ bf16 sG[64 * LD128];
    __shared__ bf16 sH[64 * LD128];
    __shared__ int sD[64];
    __shared__ int sA[64];

    const int t = threadIdx.x;
    const int wave = t >> 6, lane = t & 63;
    const int l15 = lane & 15, quad = lane >> 4;

    // per-wave B fragments in registers: n-tiles {2*wave, 2*wave+1}
    bf16x8 w1f[2][4], w2f[2][4];
    float bias1[2], bias2[2];
    #pragma unroll
    for (int j = 0; j < 2; ++j) {
        const int n = (wave * 2 + j) * 16 + l15;
        bias1[j] = b1[n];
        bias2[j] = b2[n];
        #pragma unroll
        for (int kt = 0; kt < 4; ++kt) {
            bf16x8 f1, f2;
            #pragma unroll
            for (int e = 0; e < 8; ++e) {
                int k = kt * 32 + quad * 8 + e;
                f1[e] = (bf16)W1[k * 128 + n];
                f2[e] = (bf16)W2[k * 128 + n];
            }
            w1f[j][kt] = f1;
            w2f[j][kt] = f2;
        }
    }

    for (int tile = blockIdx.x; tile < numTiles; tile += gridDim.x) {
        __syncthreads();
        const int base = tile * 64;
        {   // gather: 4 threads per row, each 32 cols of the 128-wide input
            const int r = t >> 2, p = t & 3;
            const int s = base + r;
            int slot = -1, a = 0, i0 = 0, i1 = 0, d = -1;
            if (s < S) {
                slot = list[s];
                int e = slot >> 1;
                a = slot & 1;
                i0 = idx[2 * e];
                i1 = idx[2 * e + 1];
                d = a ? i1 : i0;
            }
            if (p == 0) { sD[r] = d; sA[r] = a; }
            if (slot >= 0) {
                const int src_id = (p < 2) ? i0 : i1;
                if (BF16EMB) {
                    const uint4* src = (const uint4*)(embb + (size_t)src_id * 64 + (p & 1) * 32);
                    uint4* dst = (uint4*)&sG[r * LD128 + p * 32];
                    dst[0] = src[0];
                    dst[1] = src[1];
                    dst[2] = src[2];
                    dst[3] = src[3];
                } else {
                    const float4* src = (const float4*)(emb + (size_t)src_id * 64 + (p & 1) * 32);
                    const int cbase = p * 32;
                    #pragma unroll
                    for (int i = 0; i < 8; ++i) {
                        float4 v = src[i];
                        int c = cbase + i * 4;
                        sG[r * LD128 + c + 0] = (bf16)v.x;
                        sG[r * LD128 + c + 1] = (bf16)v.y;
                        sG[r * LD128 + c + 2] = (bf16)v.z;
                        sG[r * LD128 + c + 3] = (bf16)v.w;
                    }
                }
            }
        }
        __syncthreads();

        // GEMM1 over all 4 m-tiles, this wave's 2 n-tiles
        f32x4 acc[4][2];
        #pragma unroll
        for (int mt = 0; mt < 4; ++mt)
            #pragma unroll
            for (int j = 0; j < 2; ++j) acc[mt][j] = (f32x4){0.f, 0.f, 0.f, 0.f};
        #pragma unroll
        for (int mt = 0; mt < 4; ++mt) {
            #pragma unroll
            for (int kt = 0; kt < 4; ++kt) {
                bf16x8 a = *(const bf16x8*)&sG[(mt * 16 + l15) * LD128 + kt * 32 + quad * 8];
                #pragma unroll
                for (int j = 0; j < 2; ++j) acc[mt][j] = mfma16(a, w1f[j][kt], acc[mt][j]);
            }
        }
        #pragma unroll
        for (int mt = 0; mt < 4; ++mt)
            #pragma unroll
            for (int j = 0; j < 2; ++j) {
                #pragma unroll
                for (int r = 0; r < 4; ++r) {
                    float v = acc[mt][j][r] + bias1[j];
                    v = v > 0.f ? v : 0.f;
                    sH[(mt * 16 + quad * 4 + r) * LD128 + (wave * 2 + j) * 16 + l15] = (bf16)v;
                }
            }
        __syncthreads();

        // GEMM2 (full 128 cols; only the slot's arg slice is scattered)
        f32x4 acc2[4][2];
        #pragma unroll
        for (int mt = 0; mt < 4; ++mt)
            #pragma unroll
            for (int j = 0; j < 2; ++j) acc2[mt][j] = (f32x4){0.f, 0.f, 0.f, 0.f};
        #pragma unroll
        for (int mt = 0; mt < 4; ++mt) {
            #pragma unroll
            for (int kt = 0; kt < 4; ++kt) {
                bf16x8 a = *(const bf16x8*)&sH[(mt * 16 + l15) * LD128 + kt * 32 + quad * 8];
                #pragma unroll
                for (int j = 0; j < 2; ++j) acc2[mt][j] = mfma16(a, w2f[j][kt], acc2[mt][j]);
            }
        }
        // stage full message rows (bias included) back into sG
        #pragma unroll
        for (int mt = 0; mt < 4; ++mt)
            #pragma unroll
            for (int j = 0; j < 2; ++j) {
                #pragma unroll
                for (int r = 0; r < 4; ++r)
                    sG[(mt * 16 + quad * 4 + r) * LD128 + (wave * 2 + j) * 16 + l15] =
                        (bf16)(acc2[mt][j][r] + bias2[j]);
            }
        __syncthreads();

        // segment-reduce runs of equal dest, then scatter. col = lane (64 cols),
        // row-group = wave -> run boundaries are wave-uniform (no divergence).
        {
            const int c = lane;
            const int g = wave;
            float sum = 0.f;
            int prev = sD[g * 16];
            #pragma unroll
            for (int r16 = 0; r16 < 16; ++r16) {
                int row = g * 16 + r16;
                int d = sD[row];
                if (d != prev) {
                    if (prev >= 0) atomicAdd(&agg[(size_t)prev * 64 + c], sum);
                    sum = 0.f;
                    prev = d;
                }
                sum += (float)sG[row * LD128 + sA[row] * 64 + c];
            }
            if (prev >= 0) atomicAdd(&agg[(size_t)prev * 64 + c], sum);
        }
    }
}

// ---------------------------------------------------------------------------
// fallback atomic kernels (round-1 behavior) if workspace is too small
// ---------------------------------------------------------------------------
__global__ __launch_bounds__(256) void rel1_atomic_kernel(
    const float* __restrict__ emb, const int* __restrict__ idx,
    const float* __restrict__ W1, const float* __restrict__ b1,
    const float* __restrict__ W2, const float* __restrict__ b2,
    float* __restrict__ agg, int M, int numTiles)
{
    __shared__ bf16 sW1t[64 * LD64];
    __shared__ bf16 sW2t[64 * LD64];
    __shared__ bf16 sG[64 * LD64];
    __shared__ bf16 sH[64 * LD64];
    __shared__ float sB1[64], sB2[64];
    __shared__ int sIdx[64];

    const int t = threadIdx.x;
    const int wave = t >> 6, lane = t & 63;
    const int l15 = lane & 15, quad = lane >> 4;

    for (int i = t; i < 64 * 64; i += 256) {
        int k = i >> 6, n = i & 63;
        sW1t[n * LD64 + k] = (bf16)W1[i];
        sW2t[n * LD64 + k] = (bf16)W2[i];
    }
    if (t < 64) { sB1[t] = b1[t]; sB2[t] = b2[t]; }

    for (int tile = blockIdx.x; tile < numTiles; tile += gridDim.x) {
        __syncthreads();
        const int base = tile * 64;
        {
            const int r = t >> 2, p = t & 3;
            const int R = base + r;
            int id = -1;
            if (R < M) id = idx[R];
            if (p == 0) sIdx[r] = id;
            if (id >= 0) {
                const float4* src = (const float4*)(emb + (size_t)id * 64 + p * 16);
                #pragma unroll
                for (int i = 0; i < 4; ++i) {
                    float4 v = src[i];
                    int c = p * 16 + i * 4;
                    sG[r * LD64 + c + 0] = (bf16)v.x;
                    sG[r * LD64 + c + 1] = (bf16)v.y;
                    sG[r * LD64 + c + 2] = (bf16)v.z;
                    sG[r * LD64 + c + 3] = (bf16)v.w;
                }
            }
        }
        __syncthreads();

        f32x4 acc[4];
        #pragma unroll
        for (int nt = 0; nt < 4; ++nt) acc[nt] = (f32x4){0.f, 0.f, 0.f, 0.f};
        #pragma unroll
        for (int kt = 0; kt < 2; ++kt) {
            bf16x8 a = *(const bf16x8*)&sG[(wave * 16 + l15) * LD64 + kt * 32 + quad * 8];
            #pragma unroll
            for (int nt = 0; nt < 4; ++nt) {
                bf16x8 bf = *(const bf16x8*)&sW1t[(nt * 16 + l15) * LD64 + kt * 32 + quad * 8];
                acc[nt] = mfma16(a, bf, acc[nt]);
            }
        }
        #pragma unroll
        for (int nt = 0; nt < 4; ++nt) {
            float bias = sB1[nt * 16 + l15];
            #pragma unroll
            for (int r = 0; r < 4; ++r) {
                float v = acc[nt][r] + bias;
                v = v > 0.f ? v : 0.f;
                sH[(wave * 16 + quad * 4 + r) * LD64 + nt * 16 + l15] = (bf16)v;
            }
        }
        __syncthreads();

        f32x4 acc2[4];
        #pragma unroll
        for (int nt = 0; nt < 4; ++nt) acc2[nt] = (f32x4){0.f, 0.f, 0.f, 0.f};
        #pragma unroll
        for (int kt = 0; kt < 2; ++kt) {
            bf16x8 a = *(const bf16x8*)&sH[(wave * 16 + l15) * LD64 + kt * 32 + quad * 8];
            #pragma unroll
            for (int nt = 0; nt < 4; ++nt) {
                bf16x8 bf = *(const bf16x8*)&sW2t[(nt * 16 + l15) * LD64 + kt * 32 + quad * 8];
                acc2[nt] = mfma16(a, bf, acc2[nt]);
            }
        }
        #pragma unroll
        for (int nt = 0; nt < 4; ++nt) {
            float bias = sB2[nt * 16 + l15];
            #pragma unroll
            for (int r = 0; r < 4; ++r) {
                int row = wave * 16 + quad * 4 + r;
                int id = sIdx[row];
                if (id >= 0)
                    atomicAdd(&agg[(size_t)id * 64 + nt * 16 + l15], acc2[nt][r] + bias);
            }
        }
    }
}

__global__ __launch_bounds__(256) void rel2_atomic_kernel(
    const float* __restrict__ emb, const int* __restrict__ idx,
    const float* __restrict__ W1, const float* __restrict__ b1,
    const float* __restrict__ W2, const float* __restrict__ b2,
    float* __restrict__ agg, int M, int numTiles)
{
    __shared__ bf16 sG[64 * LD128];
    __shared__ bf16 sH[64 * LD128];
    __shared__ int sIdx[64 * 2];

    const int t = threadIdx.x;
    const int wave = t >> 6, lane = t & 63;
    const int l15 = lane & 15, quad = lane >> 4;

    bf16x8 w1f[2][4], w2f[2][4];
    float bias1[2], bias2[2];
    #pragma unroll
    for (int j = 0; j < 2; ++j) {
        const int n = (wave * 2 + j) * 16 + l15;
        bias1[j] = b1[n];
        bias2[j] = b2[n];
        #pragma unroll
        for (int kt = 0; kt < 4; ++kt) {
            bf16x8 f1, f2;
            #pragma unroll
            for (int e = 0; e < 8; ++e) {
                int k = kt * 32 + quad * 8 + e;
                f1[e] = (bf16)W1[k * 128 + n];
                f2[e] = (bf16)W2[k * 128 + n];
            }
            w1f[j][kt] = f1;
            w2f[j][kt] = f2;
        }
    }

    for (int tile = blockIdx.x; tile < numTiles; tile += gridDim.x) {
        __syncthreads();
        const int base = tile * 64;
        {
            const int r = t >> 2, p = t & 3;
            const int R = base + r;
            int i0 = -1, i1 = -1;
            if (R < M) { i0 = idx[R * 2]; i1 = idx[R * 2 + 1]; }
            if (p == 0) { sIdx[r * 2] = i0; sIdx[r * 2 + 1] = i1; }
            if (R < M) {
                const int src_id = (p < 2) ? i0 : i1;
                const float4* src = (const float4*)(emb + (size_t)src_id * 64 + (p & 1) * 32);
                const int cbase = p * 32;
                #pragma unroll
                for (int i = 0; i < 8; ++i) {
                    float4 v = src[i];
                    int c = cbase + i * 4;
                    sG[r * LD128 + c + 0] = (bf16)v.x;
                    sG[r * LD128 + c + 1] = (bf16)v.y;
                    sG[r * LD128 + c + 2] = (bf16)v.z;
                    sG[r * LD128 + c + 3] = (bf16)v.w;
                }
            }
        }
        __syncthreads();

        f32x4 acc[4][2];
        #pragma unroll
        for (int mt = 0; mt < 4; ++mt)
            #pragma unroll
            for (int j = 0; j < 2; ++j) acc[mt][j] = (f32x4){0.f, 0.f, 0.f, 0.f};
        #pragma unroll
        for (int mt = 0; mt < 4; ++mt) {
            #pragma unroll
            for (int kt = 0; kt < 4; ++kt) {
                bf16x8 a = *(const bf16x8*)&sG[(mt * 16 + l15) * LD128 + kt * 32 + quad * 8];
                #pragma unroll
                for (int j = 0; j < 2; ++j) acc[mt][j] = mfma16(a, w1f[j][kt], acc[mt][j]);
            }
        }
        #pragma unroll
        for (int mt = 0; mt < 4; ++mt)
            #pragma unroll
            for (int j = 0; j < 2; ++j) {
                #pragma unroll
                for (int r = 0; r < 4; ++r) {
                    float v = acc[mt][j][r] + bias1[j];
                    v = v > 0.f ? v : 0.f;
                    sH[(mt * 16 + quad * 4 + r) * LD128 + (wave * 2 + j) * 16 + l15] = (bf16)v;
                }
            }
        __syncthreads();

        f32x4 acc2[4][2];
        #pragma unroll
        for (int mt = 0; mt < 4; ++mt)
            #pragma unroll
            for (int j = 0; j < 2; ++j) acc2[mt][j] = (f32x4){0.f, 0.f, 0.f, 0.f};
        #pragma unroll
        for (int mt = 0; mt < 4; ++mt) {
            #pragma unroll
            for (int kt = 0; kt < 4; ++kt) {
                bf16x8 a = *(const bf16x8*)&sH[(mt * 16 + l15) * LD128 + kt * 32 + quad * 8];
                #pragma unroll
                for (int j = 0; j < 2; ++j) acc2[mt][j] = mfma16(a, w2f[j][kt], acc2[mt][j]);
            }
        }
        #pragma unroll
        for (int mt = 0; mt < 4; ++mt) {
            #pragma unroll
            for (int j = 0; j < 2; ++j) {
                const int col = (wave * 2 + j) * 16 + l15;
                const int sel = col >> 6;
                const int c = col & 63;
                #pragma unroll
                for (int r = 0; r < 4; ++r) {
                    int row = mt * 16 + quad * 4 + r;
                    int id = sIdx[row * 2 + sel];
                    if (id >= 0)
                        atomicAdd(&agg[(size_t)id * 64 + c], acc2[mt][j][r] + bias2[j]);
                }
            }
        }
    }
}

// ---------------------------------------------------------------------------
// update: out = relu([emb||agg] @ W1 + b1) @ W2 + b2
// ---------------------------------------------------------------------------
__global__ __launch_bounds__(256) void update_kernel(
    const float* __restrict__ emb, const float* __restrict__ agg,
    const float* __restrict__ W1, const float* __restrict__ b1,  // 128x64, 64
    const float* __restrict__ W2, const float* __restrict__ b2,  // 64x64, 64
    float* __restrict__ out, int N, int numTiles)
{
    __shared__ bf16 sW1t[64 * LD128];  // [n][k], k=128
    __shared__ bf16 sW2t[64 * LD64];   // [n][k], k=64
    __shared__ bf16 sU[64 * LD128];
    __shared__ bf16 sH[64 * LD64];
    __shared__ float sB1[64], sB2[64];

    const int t = threadIdx.x;
    const int wave = t >> 6, lane = t & 63;
    const int l15 = lane & 15, quad = lane >> 4;

    for (int i = t; i < 128 * 64; i += 256) {
        int k = i >> 6, n = i & 63;
        sW1t[n * LD128 + k] = (bf16)W1[i];
    }
    for (int i = t; i < 64 * 64; i += 256) {
        int k = i >> 6, n = i & 63;
        sW2t[n * LD64 + k] = (bf16)W2[i];
    }
    if (t < 64) { sB1[t] = b1[t]; sB2[t] = b2[t]; }

    for (int tile = blockIdx.x; tile < numTiles; tile += gridDim.x) {
        __syncthreads();
        const int base = tile * 64;
        {
            const int r = t >> 2, p = t & 3;
            const int R = base + r;
            if (R < N) {
                const float* srcp = (p < 2) ? (emb + (size_t)R * 64 + p * 32)
                                            : (agg + (size_t)R * 64 + (p - 2) * 32);
                const float4* src = (const float4*)srcp;
                const int cbase = p * 32;
                #pragma unroll
                for (int i = 0; i < 8; ++i) {
                    float4 v = src[i];
                    int c = cbase + i * 4;
                    sU[r * LD128 + c + 0] = (bf16)v.x;
                    sU[r * LD128 + c + 1] = (bf16)v.y;
                    sU[r * LD128 + c + 2] = (bf16)v.z;
                    sU[r * LD128 + c + 3] = (bf16)v.w;
                }
            }
        }
        __syncthreads();

        f32x4 acc[4];
        #pragma unroll
        for (int nt = 0; nt < 4; ++nt) acc[nt] = (f32x4){0.f, 0.f, 0.f, 0.f};
        #pragma unroll
        for (int kt = 0; kt < 4; ++kt) {
            bf16x8 a = *(const bf16x8*)&sU[(wave * 16 + l15) * LD128 + kt * 32 + quad * 8];
            #pragma unroll
            for (int nt = 0; nt < 4; ++nt) {
                bf16x8 bf = *(const bf16x8*)&sW1t[(nt * 16 + l15) * LD128 + kt * 32 + quad * 8];
                acc[nt] = mfma16(a, bf, acc[nt]);
            }
        }
        #pragma unroll
        for (int nt = 0; nt < 4; ++nt) {
            float bias = sB1[nt * 16 + l15];
            #pragma unroll
            for (int r = 0; r < 4; ++r) {
                float v = acc[nt][r] + bias;
                v = v > 0.f ? v : 0.f;
                sH[(wave * 16 + quad * 4 + r) * LD64 + nt * 16 + l15] = (bf16)v;
            }
        }
        __syncthreads();

        f32x4 acc2[4];
        #pragma unroll
        for (int nt = 0; nt < 4; ++nt) acc2[nt] = (f32x4){0.f, 0.f, 0.f, 0.f};
        #pragma unroll
        for (int kt = 0; kt < 2; ++kt) {
            bf16x8 a = *(const bf16x8*)&sH[(wave * 16 + l15) * LD64 + kt * 32 + quad * 8];
            #pragma unroll
            for (int nt = 0; nt < 4; ++nt) {
                bf16x8 bf = *(const bf16x8*)&sW2t[(nt * 16 + l15) * LD64 + kt * 32 + quad * 8];
                acc2[nt] = mfma16(a, bf, acc2[nt]);
            }
        }
        #pragma unroll
        for (int nt = 0; nt < 4; ++nt) {
            float bias = sB2[nt * 16 + l15];
            #pragma unroll
            for (int r = 0; r < 4; ++r) {
                int row = wave * 16 + quad * 4 + r;
                int R = base + row;
                if (R < N)
                    out[(size_t)R * 64 + nt * 16 + l15] = acc2[nt][r] + bias;
            }
        }
    }
}

extern "C" void kernel_launch(void* const* d_in, const int* in_sizes, int n_in,
                              void* d_out, int out_size, void* d_ws, size_t ws_size,
                              hipStream_t stream) {
    const float* emb    = (const float*)d_in[0];
    const int*   rel1   = (const int*)d_in[1];
    const int*   rel2   = (const int*)d_in[2];
    const float* m1W1   = (const float*)d_in[3];
    const float* m1b1   = (const float*)d_in[4];
    const float* m1W2   = (const float*)d_in[5];
    const float* m1b2   = (const float*)d_in[6];
    const float* m2W1   = (const float*)d_in[7];
    const float* m2b1   = (const float*)d_in[8];
    const float* m2W2   = (const float*)d_in[9];
    const float* m2b2   = (const float*)d_in[10];
    const float* uW1    = (const float*)d_in[11];
    const float* ub1    = (const float*)d_in[12];
    const float* uW2    = (const float*)d_in[13];
    const float* ub2    = (const float*)d_in[14];

    const int N  = in_sizes[0] / 64;   // 100000
    const int M1 = in_sizes[1];        // 500000
    const int M2 = in_sizes[2] / 2;    // 1000000
    const int S2 = 2 * M2;             // 2M arg-slots

    // workspace layout (256B-aligned)
    char* ws = (char*)d_ws;
    size_t off = 0;
    auto alloc = [&](size_t bytes) -> char* {
        char* p = ws + off;
        off += (bytes + 255) & ~(size_t)255;
        return p;
    };
    float* agg   = (float*)alloc((size_t)N * 64 * sizeof(float));   // 25.6 MB
    // cnt1+cnt2 as ONE contiguous block so a single memset covers both exactly
    // (round-4 crash: per-alloc 256B padding left cnt2's tail poisoned).
    int*   cnt1  = (int*)  alloc(2 * (size_t)N * sizeof(int));
    int*   cnt2  = cnt1 + N;
    int*   pos2  = (int*)  alloc((size_t)N * sizeof(int));
    int*   list2 = (int*)  alloc((size_t)S2 * sizeof(int));          // 8 MB
    const size_t needBase = off;
    bf16* embb = (bf16*)alloc((size_t)N * 64 * sizeof(bf16));        // 12.8 MB
    const size_t needBf16 = off;

    const bool sorted  = (ws_size >= needBase);
    const bool bf16emb = (ws_size >= needBf16);

    const int tu = (N + 63) / 64;

    if (sorted) {
        hipMemsetAsync(cnt1, 0, 2 * (size_t)N * sizeof(int), stream);  // cnt1+cnt2
        if (bf16emb) {
            const int n8 = N * 64 / 8;
            convert_kernel<<<3200, 256, 0, stream>>>(emb, embb, n8);
        }
        const int total = M1 + S2;
        hist2_kernel<<<4096, 256, 0, stream>>>(rel1, rel2, cnt1, cnt2, M1, total);
        scan_kernel<<<1, SCAN_T, 0, stream>>>(cnt2, pos2, N);
        fill_kernel<<<4096, 256, 0, stream>>>(rel2, pos2, list2, S2);
        // rel1 contribution: plain stores initialize agg (no memset needed)
        rel1_dense_kernel<<<tu, 256, 0, stream>>>(emb, cnt1, m1W1, m1b1, m1W2, m1b2,
                                                  agg, N, tu);
        const int t2 = (S2 + 63) / 64;
        const int g2 = t2 < 2048 ? t2 : 2048;
        if (bf16emb)
            rel2_sorted_kernel<true><<<g2, 256, 0, stream>>>(
                emb, embb, rel2, m2W1, m2b1, m2W2, m2b2, list2, agg, S2, t2);
        else
            rel2_sorted_kernel<false><<<g2, 256, 0, stream>>>(
                emb, embb, rel2, m2W1, m2b1, m2W2, m2b2, list2, agg, S2, t2);
    } else {
        // fallback: scalar-atomic scatter path (round-1 behavior)
        hipMemsetAsync(agg, 0, (size_t)N * 64 * sizeof(float), stream);
        const int t1 = (M1 + 63) / 64;
        const int g1 = t1 < 1024 ? t1 : 1024;
        rel1_atomic_kernel<<<g1, 256, 0, stream>>>(emb, rel1, m1W1, m1b1, m1W2, m1b2,
                                                   agg, M1, t1);
        const int t2 = (M2 + 63) / 64;
        const int g2 = t2 < 2048 ? t2 : 2048;
        rel2_atomic_kernel<<<g2, 256, 0, stream>>>(emb, rel2, m2W1, m2b1, m2W2, m2b2,
                                                   agg, M2, t2);
    }

    update_kernel<<<tu, 256, 0, stream>>>(emb, agg, uW1, ub1, uW2, ub2, (float*)d_out, N, tu);
}

// Round 6
// 708.162 us; speedup vs baseline: 1.2680x; 1.2680x over previous
//
#include <hip/hip_runtime.h>

typedef __bf16 bf16;
typedef bf16 bf16x8 __attribute__((ext_vector_type(8)));
typedef float f32x4 __attribute__((ext_vector_type(4)));

#define LD64  80   // padded LDS row stride (elems) for 64-wide tiles
#define LD128 144  // padded LDS row stride for 128-wide tiles

static __device__ __forceinline__ f32x4 mfma16(bf16x8 a, bf16x8 b, f32x4 c) {
    return __builtin_amdgcn_mfma_f32_16x16x32_bf16(a, b, c, 0, 0, 0);
}

// ---------------------------------------------------------------------------
// convert: emb fp32 -> bf16
// ---------------------------------------------------------------------------
__global__ __launch_bounds__(256) void convert_kernel(
    const float* __restrict__ src, bf16* __restrict__ dst, int n8)
{
    int i = blockIdx.x * 256 + threadIdx.x;
    const int stride = gridDim.x * 256;
    for (; i < n8; i += stride) {
        const float4* s = (const float4*)(src + (size_t)i * 8);
        float4 a = s[0], b = s[1];
        bf16x8 v = {(bf16)a.x, (bf16)a.y, (bf16)a.z, (bf16)a.w,
                    (bf16)b.x, (bf16)b.y, (bf16)b.z, (bf16)b.w};
        *(bf16x8*)(dst + (size_t)i * 8) = v;
    }
}

// ---------------------------------------------------------------------------
// hist2: two clean coalesced loops (round-5's fused branchy loop split)
// ---------------------------------------------------------------------------
__global__ __launch_bounds__(256) void hist2_kernel(
    const int* __restrict__ idx1, const int* __restrict__ idx2,
    int* __restrict__ cnt1, int* __restrict__ cnt2, int M1, int S2)
{
    const int gid = blockIdx.x * 256 + threadIdx.x;
    const int stride = gridDim.x * 256;
    for (int s = gid; s < M1; s += stride) atomicAdd(&cnt1[idx1[s]], 1);
    for (int s = gid; s < S2; s += stride) atomicAdd(&cnt2[idx2[s]], 1);
}

// ---------------------------------------------------------------------------
// 3-phase multi-block exclusive scan (round-5's single-block scan ran on ONE
// CU with 64-different-cache-line wave loads -> ~400us; this is ~10us).
// Block = 256 threads x 8 contiguous elems = 2048 elems, int4 loads.
// ---------------------------------------------------------------------------
__global__ __launch_bounds__(256) void scanA_kernel(
    const int* __restrict__ cnt, int* __restrict__ bsum, int N)
{
    __shared__ int red[256];
    const int t = threadIdx.x;
    const int base = blockIdx.x * 2048 + t * 8;
    int s = 0;
    if (base + 8 <= N) {
        int4 a = *(const int4*)(cnt + base);
        int4 c = *(const int4*)(cnt + base + 4);
        s = a.x + a.y + a.z + a.w + c.x + c.y + c.z + c.w;
    } else {
        for (int i = 0; i < 8; ++i) { int ix = base + i; if (ix < N) s += cnt[ix]; }
    }
    red[t] = s;
    __syncthreads();
    for (int o = 128; o > 0; o >>= 1) {
        if (t < o) red[t] += red[t + o];
        __syncthreads();
    }
    if (t == 0) bsum[blockIdx.x] = red[0];
}

__global__ __launch_bounds__(256) void scanB_kernel(int* __restrict__ bsum, int B)
{
    __shared__ int s[256];
    const int t = threadIdx.x;
    int v = (t < B) ? bsum[t] : 0;
    s[t] = v;
    __syncthreads();
    for (int o = 1; o < 256; o <<= 1) {
        int x = (t >= o) ? s[t - o] : 0;
        __syncthreads();
        s[t] += x;
        __syncthreads();
    }
    if (t < B) bsum[t] = s[t] - v;  // exclusive
}

__global__ __launch_bounds__(256) void scanC_kernel(
    const int* __restrict__ cnt, const int* __restrict__ bsum,
    int* __restrict__ pos, int N)
{
    __shared__ int red[256];
    const int t = threadIdx.x;
    const int base = blockIdx.x * 2048 + t * 8;
    int v[8];
    int s = 0;
    #pragma unroll
    for (int i = 0; i < 8; ++i) {
        int ix = base + i;
        v[i] = (ix < N) ? cnt[ix] : 0;
        s += v[i];
    }
    red[t] = s;
    __syncthreads();
    const int mine = s;
    for (int o = 1; o < 256; o <<= 1) {
        int x = (t >= o) ? red[t - o] : 0;
        __syncthreads();
        red[t] += x;
        __syncthreads();
    }
    int excl = red[t] - mine + bsum[blockIdx.x];
    #pragma unroll
    for (int i = 0; i < 8; ++i) {
        int ix = base + i;
        if (ix < N) { pos[ix] = excl; excl += v[i]; }
    }
}

// ---------------------------------------------------------------------------
// fill: dest-sorted arg-slot list for rel2 via per-node atomic cursors.
// ---------------------------------------------------------------------------
__global__ __launch_bounds__(256) void fill_kernel(
    const int* __restrict__ idx2, int* __restrict__ pos,
    int* __restrict__ list, int S)
{
    int s = blockIdx.x * 256 + threadIdx.x;
    const int stride = gridDim.x * 256;
    for (; s < S; s += stride) {
        int p = atomicAdd(&pos[idx2[s]], 1);
        list[p] = s;
    }
}

// ---------------------------------------------------------------------------
// rel1_dense: agg[n] = cnt1[n] * MLP1(emb[n]). Dense, plain stores.
// ---------------------------------------------------------------------------
__global__ __launch_bounds__(256) void rel1_dense_kernel(
    const float* __restrict__ emb, const int* __restrict__ cnt,
    const float* __restrict__ W1, const float* __restrict__ b1,
    const float* __restrict__ W2, const float* __restrict__ b2,
    float* __restrict__ agg, int N, int numTiles)
{
    __shared__ bf16 sW1t[64 * LD64];   // [n][k]
    __shared__ bf16 sW2t[64 * LD64];
    __shared__ bf16 sG[64 * LD64];
    __shared__ bf16 sH[64 * LD64];
    __shared__ float sB1[64], sB2[64];

    const int t = threadIdx.x;
    const int wave = t >> 6, lane = t & 63;
    const int l15 = lane & 15, quad = lane >> 4;

    for (int i = t; i < 64 * 64; i += 256) {
        int k = i >> 6, n = i & 63;
        sW1t[n * LD64 + k] = (bf16)W1[i];
        sW2t[n * LD64 + k] = (bf16)W2[i];
    }
    if (t < 64) { sB1[t] = b1[t]; sB2[t] = b2[t]; }

    for (int tile = blockIdx.x; tile < numTiles; tile += gridDim.x) {
        __syncthreads();
        const int base = tile * 64;
        {
            const int r = t >> 2, p = t & 3;
            const int R = base + r;
            if (R < N) {
                const float4* src = (const float4*)(emb + (size_t)R * 64 + p * 16);
                #pragma unroll
                for (int i = 0; i < 4; ++i) {
                    float4 v = src[i];
                    int c = p * 16 + i * 4;
                    sG[r * LD64 + c + 0] = (bf16)v.x;
                    sG[r * LD64 + c + 1] = (bf16)v.y;
                    sG[r * LD64 + c + 2] = (bf16)v.z;
                    sG[r * LD64 + c + 3] = (bf16)v.w;
                }
            }
        }
        __syncthreads();

        f32x4 acc[4];
        #pragma unroll
        for (int nt = 0; nt < 4; ++nt) acc[nt] = (f32x4){0.f, 0.f, 0.f, 0.f};
        #pragma unroll
        for (int kt = 0; kt < 2; ++kt) {
            bf16x8 a = *(const bf16x8*)&sG[(wave * 16 + l15) * LD64 + kt * 32 + quad * 8];
            #pragma unroll
            for (int nt = 0; nt < 4; ++nt) {
                bf16x8 bf = *(const bf16x8*)&sW1t[(nt * 16 + l15) * LD64 + kt * 32 + quad * 8];
                acc[nt] = mfma16(a, bf, acc[nt]);
            }
        }
        #pragma unroll
        for (int nt = 0; nt < 4; ++nt) {
            float bias = sB1[nt * 16 + l15];
            #pragma unroll
            for (int r = 0; r < 4; ++r) {
                float v = acc[nt][r] + bias;
                v = v > 0.f ? v : 0.f;
                sH[(wave * 16 + quad * 4 + r) * LD64 + nt * 16 + l15] = (bf16)v;
            }
        }
        __syncthreads();

        f32x4 acc2[4];
        #pragma unroll
        for (int nt = 0; nt < 4; ++nt) acc2[nt] = (f32x4){0.f, 0.f, 0.f, 0.f};
        #pragma unroll
        for (int kt = 0; kt < 2; ++kt) {
            bf16x8 a = *(const bf16x8*)&sH[(wave * 16 + l15) * LD64 + kt * 32 + quad * 8];
            #pragma unroll
            for (int nt = 0; nt < 4; ++nt) {
                bf16x8 bf = *(const bf16x8*)&sW2t[(nt * 16 + l15) * LD64 + kt * 32 + quad * 8];
                acc2[nt] = mfma16(a, bf, acc2[nt]);
            }
        }
        #pragma unroll
        for (int nt = 0; nt < 4; ++nt) {
            float bias = sB2[nt * 16 + l15];
            #pragma unroll
            for (int r = 0; r < 4; ++r) {
                int row = wave * 16 + quad * 4 + r;
                int R = base + row;
                if (R < N) {
                    float scale = (float)cnt[R];
                    agg[(size_t)R * 64 + nt * 16 + l15] = scale * (acc2[nt][r] + bias);
                }
            }
        }
    }
}

// ---------------------------------------------------------------------------
// rel2_sorted: dest-sorted arg-slots; full 128-wide MLP per slot; wave-local
// segment reduction of equal-dest runs before atomicAdd.
// ---------------------------------------------------------------------------
template<bool BF16EMB>
__global__ __launch_bounds__(256) void rel2_sorted_kernel(
    const float* __restrict__ emb, const bf16* __restrict__ embb,
    const int* __restrict__ idx,  // [2*M] flat
    const float* __restrict__ W1, const float* __restrict__ b1,  // 128x128, 128
    const float* __restrict__ W2, const float* __restrict__ b2,
    const int* __restrict__ list, float* __restrict__ agg,
    int S, int numTiles)
{
    __shared__ bf16 sG[64 * LD128];
    __shared__ bf16 sH[64 * LD128];
    __shared__ int sD[64];
    __shared__ int sA[64];

    const int t = threadIdx.x;
    const int wave = t >> 6, lane = t & 63;
    const int l15 = lane & 15, quad = lane >> 4;

    bf16x8 w1f[2][4], w2f[2][4];
    float bias1[2], bias2[2];
    #pragma unroll
    for (int j = 0; j < 2; ++j) {
        const int n = (wave * 2 + j) * 16 + l15;
        bias1[j] = b1[n];
        bias2[j] = b2[n];
        #pragma unroll
        for (int kt = 0; kt < 4; ++kt) {
            bf16x8 f1, f2;
            #pragma unroll
            for (int e = 0; e < 8; ++e) {
                int k = kt * 32 + quad * 8 + e;
                f1[e] = (bf16)W1[k * 128 + n];
                f2[e] = (bf16)W2[k * 128 + n];
            }
            w1f[j][kt] = f1;
            w2f[j][kt] = f2;
        }
    }

    for (int tile = blockIdx.x; tile < numTiles; tile += gridDim.x) {
        __syncthreads();
        const int base = tile * 64;
        {
            const int r = t >> 2, p = t & 3;
            const int s = base + r;
            int slot = -1, a = 0, i0 = 0, i1 = 0, d = -1;
            if (s < S) {
                slot = list[s];
                int e = slot >> 1;
                a = slot & 1;
                i0 = idx[2 * e];
                i1 = idx[2 * e + 1];
                d = a ? i1 : i0;
            }
            if (p == 0) { sD[r] = d; sA[r] = a; }
            if (slot >= 0) {
                const int src_id = (p < 2) ? i0 : i1;
                if (BF16EMB) {
                    const uint4* src = (const uint4*)(embb + (size_t)src_id * 64 + (p & 1) * 32);
                    uint4* dst = (uint4*)&sG[r * LD128 + p * 32];
                    dst[0] = src[0];
                    dst[1] = src[1];
                    dst[2] = src[2];
                    dst[3] = src[3];
                } else {
                    const float4* src = (const float4*)(emb + (size_t)src_id * 64 + (p & 1) * 32);
                    const int cbase = p * 32;
                    #pragma unroll
                    for (int i = 0; i < 8; ++i) {
                        float4 v = src[i];
                        int c = cbase + i * 4;
                        sG[r * LD128 + c + 0] = (bf16)v.x;
                        sG[r * LD128 + c + 1] = (bf16)v.y;
                        sG[r * LD128 + c + 2] = (bf16)v.z;
                        sG[r * LD128 + c + 3] = (bf16)v.w;
                    }
                }
            }
        }
        __syncthreads();

        f32x4 acc[4][2];
        #pragma unroll
        for (int mt = 0; mt < 4; ++mt)
            #pragma unroll
            for (int j = 0; j < 2; ++j) acc[mt][j] = (f32x4){0.f, 0.f, 0.f, 0.f};
        #pragma unroll
        for (int mt = 0; mt < 4; ++mt) {
            #pragma unroll
            for (int kt = 0; kt < 4; ++kt) {
                bf16x8 a = *(const bf16x8*)&sG[(mt * 16 + l15) * LD128 + kt * 32 + quad * 8];
                #pragma unroll
                for (int j = 0; j < 2; ++j) acc[mt][j] = mfma16(a, w1f[j][kt], acc[mt][j]);
            }
        }
        #pragma unroll
        for (int mt = 0; mt < 4; ++mt)
            #pragma unroll
            for (int j = 0; j < 2; ++j) {
                #pragma unroll
                for (int r = 0; r < 4; ++r) {
                    float v = acc[mt][j][r] + bias1[j];
                    v = v > 0.f ? v : 0.f;
                    sH[(mt * 16 + quad * 4 + r) * LD128 + (wave * 2 + j) * 16 + l15] = (bf16)v;
                }
            }
        __syncthreads();

        f32x4 acc2[4][2];
        #pragma unroll
        for (int mt = 0; mt < 4; ++mt)
            #pragma unroll
            for (int j = 0; j < 2; ++j) acc2[mt][j] = (f32x4){0.f, 0.f, 0.f, 0.f};
        #pragma unroll
        for (int mt = 0; mt < 4; ++mt) {
            #pragma unroll
            for (int kt = 0; kt < 4; ++kt) {
                bf16x8 a = *(const bf16x8*)&sH[(mt * 16 + l15) * LD128 + kt * 32 + quad * 8];
                #pragma unroll
                for (int j = 0; j < 2; ++j) acc2[mt][j] = mfma16(a, w2f[j][kt], acc2[mt][j]);
            }
        }
        #pragma unroll
        for (int mt = 0; mt < 4; ++mt)
            #pragma unroll
            for (int j = 0; j < 2; ++j) {
                #pragma unroll
                for (int r = 0; r < 4; ++r)
                    sG[(mt * 16 + quad * 4 + r) * LD128 + (wave * 2 + j) * 16 + l15] =
                        (bf16)(acc2[mt][j][r] + bias2[j]);
            }
        __syncthreads();

        {
            const int c = lane;
            const int g = wave;
            float sum = 0.f;
            int prev = sD[g * 16];
            #pragma unroll
            for (int r16 = 0; r16 < 16; ++r16) {
                int row = g * 16 + r16;
                int d = sD[row];
                if (d != prev) {
                    if (prev >= 0) atomicAdd(&agg[(size_t)prev * 64 + c], sum);
                    sum = 0.f;
                    prev = d;
                }
                sum += (float)sG[row * LD128 + sA[row] * 64 + c];
            }
            if (prev >= 0) atomicAdd(&agg[(size_t)prev * 64 + c], sum);
        }
    }
}

// ---------------------------------------------------------------------------
// fallback atomic kernels (round-1 behavior) if workspace is too small
// ---------------------------------------------------------------------------
__global__ __launch_bounds__(256) void rel1_atomic_kernel(
    const float* __restrict__ emb, const int* __restrict__ idx,
    const float* __restrict__ W1, const float* __restrict__ b1,
    const float* __restrict__ W2, const float* __restrict__ b2,
    float* __restrict__ agg, int M, int numTiles)
{
    __shared__ bf16 sW1t[64 * LD64];
    __shared__ bf16 sW2t[64 * LD64];
    __shared__ bf16 sG[64 * LD64];
    __shared__ bf16 sH[64 * LD64];
    __shared__ float sB1[64], sB2[64];
    __shared__ int sIdx[64];

    const int t = threadIdx.x;
    const int wave = t >> 6, lane = t & 63;
    const int l15 = lane & 15, quad = lane >> 4;

    for (int i = t; i < 64 * 64; i += 256) {
        int k = i >> 6, n = i & 63;
        sW1t[n * LD64 + k] = (bf16)W1[i];
        sW2t[n * LD64 + k] = (bf16)W2[i];
    }
    if (t < 64) { sB1[t] = b1[t]; sB2[t] = b2[t]; }

    for (int tile = blockIdx.x; tile < numTiles; tile += gridDim.x) {
        __syncthreads();
        const int base = tile * 64;
        {
            const int r = t >> 2, p = t & 3;
            const int R = base + r;
            int id = -1;
            if (R < M) id = idx[R];
            if (p == 0) sIdx[r] = id;
            if (id >= 0) {
                const float4* src = (const float4*)(emb + (size_t)id * 64 + p * 16);
                #pragma unroll
                for (int i = 0; i < 4; ++i) {
                    float4 v = src[i];
                    int c = p * 16 + i * 4;
                    sG[r * LD64 + c + 0] = (bf16)v.x;
                    sG[r * LD64 + c + 1] = (bf16)v.y;
                    sG[r * LD64 + c + 2] = (bf16)v.z;
                    sG[r * LD64 + c + 3] = (bf16)v.w;
                }
            }
        }
        __syncthreads();

        f32x4 acc[4];
        #pragma unroll
        for (int nt = 0; nt < 4; ++nt) acc[nt] = (f32x4){0.f, 0.f, 0.f, 0.f};
        #pragma unroll
        for (int kt = 0; kt < 2; ++kt) {
            bf16x8 a = *(const bf16x8*)&sG[(wave * 16 + l15) * LD64 + kt * 32 + quad * 8];
            #pragma unroll
            for (int nt = 0; nt < 4; ++nt) {
                bf16x8 bf = *(const bf16x8*)&sW1t[(nt * 16 + l15) * LD64 + kt * 32 + quad * 8];
                acc[nt] = mfma16(a, bf, acc[nt]);
            }
        }
        #pragma unroll
        for (int nt = 0; nt < 4; ++nt) {
            float bias = sB1[nt * 16 + l15];
            #pragma unroll
            for (int r = 0; r < 4; ++r) {
                float v = acc[nt][r] + bias;
                v = v > 0.f ? v : 0.f;
                sH[(wave * 16 + quad * 4 + r) * LD64 + nt * 16 + l15] = (bf16)v;
            }
        }
        __syncthreads();

        f32x4 acc2[4];
        #pragma unroll
        for (int nt = 0; nt < 4; ++nt) acc2[nt] = (f32x4){0.f, 0.f, 0.f, 0.f};
        #pragma unroll
        for (int kt = 0; kt < 2; ++kt) {
            bf16x8 a = *(const bf16x8*)&sH[(wave * 16 + l15) * LD64 + kt * 32 + quad * 8];
            #pragma unroll
            for (int nt = 0; nt < 4; ++nt) {
                bf16x8 bf = *(const bf16x8*)&sW2t[(nt * 16 + l15) * LD64 + kt * 32 + quad * 8];
                acc2[nt] = mfma16(a, bf, acc2[nt]);
            }
        }
        #pragma unroll
        for (int nt = 0; nt < 4; ++nt) {
            float bias = sB2[nt * 16 + l15];
            #pragma unroll
            for (int r = 0; r < 4; ++r) {
                int row = wave * 16 + quad * 4 + r;
                int id = sIdx[row];
                if (id >= 0)
                    atomicAdd(&agg[(size_t)id * 64 + nt * 16 + l15], acc2[nt][r] + bias);
            }
        }
    }
}

__global__ __launch_bounds__(256) void rel2_atomic_kernel(
    const float* __restrict__ emb, const int* __restrict__ idx,
    const float* __restrict__ W1, const float* __restrict__ b1,
    const float* __restrict__ W2, const float* __restrict__ b2,
    float* __restrict__ agg, int M, int numTiles)
{
    __shared__ bf16 sG[64 * LD128];
    __shared__ bf16 sH[64 * LD128];
    __shared__ int sIdx[64 * 2];

    const int t = threadIdx.x;
    const int wave = t >> 6, lane = t & 63;
    const int l15 = lane & 15, quad = lane >> 4;

    bf16x8 w1f[2][4], w2f[2][4];
    float bias1[2], bias2[2];
    #pragma unroll
    for (int j = 0; j < 2; ++j) {
        const int n = (wave * 2 + j) * 16 + l15;
        bias1[j] = b1[n];
        bias2[j] = b2[n];
        #pragma unroll
        for (int kt = 0; kt < 4; ++kt) {
            bf16x8 f1, f2;
            #pragma unroll
            for (int e = 0; e < 8; ++e) {
                int k = kt * 32 + quad * 8 + e;
                f1[e] = (bf16)W1[k * 128 + n];
                f2[e] = (bf16)W2[k * 128 + n];
            }
            w1f[j][kt] = f1;
            w2f[j][kt] = f2;
        }
    }

    for (int tile = blockIdx.x; tile < numTiles; tile += gridDim.x) {
        __syncthreads();
        const int base = tile * 64;
        {
            const int r = t >> 2, p = t & 3;
            const int R = base + r;
            int i0 = -1, i1 = -1;
            if (R < M) { i0 = idx[R * 2]; i1 = idx[R * 2 + 1]; }
            if (p == 0) { sIdx[r * 2] = i0; sIdx[r * 2 + 1] = i1; }
            if (R < M) {
                const int src_id = (p < 2) ? i0 : i1;
                const float4* src = (const float4*)(emb + (size_t)src_id * 64 + (p & 1) * 32);
                const int cbase = p * 32;
                #pragma unroll
                for (int i = 0; i < 8; ++i) {
                    float4 v = src[i];
                    int c = cbase + i * 4;
                    sG[r * LD128 + c + 0] = (bf16)v.x;
                    sG[r * LD128 + c + 1] = (bf16)v.y;
                    sG[r * LD128 + c + 2] = (bf16)v.z;
                    sG[r * LD128 + c + 3] = (bf16)v.w;
                }
            }
        }
        __syncthreads();

        f32x4 acc[4][2];
        #pragma unroll
        for (int mt = 0; mt < 4; ++mt)
            #pragma unroll
            for (int j = 0; j < 2; ++j) acc[mt][j] = (f32x4){0.f, 0.f, 0.f, 0.f};
        #pragma unroll
        for (int mt = 0; mt < 4; ++mt) {
            #pragma unroll
            for (int kt = 0; kt < 4; ++kt) {
                bf16x8 a = *(const bf16x8*)&sG[(mt * 16 + l15) * LD128 + kt * 32 + quad * 8];
                #pragma unroll
                for (int j = 0; j < 2; ++j) acc[mt][j] = mfma16(a, w1f[j][kt], acc[mt][j]);
            }
        }
        #pragma unroll
        for (int mt = 0; mt < 4; ++mt)
            #pragma unroll
            for (int j = 0; j < 2; ++j) {
                #pragma unroll
                for (int r = 0; r < 4; ++r) {
                    float v = acc[mt][j][r] + bias1[j];
                    v = v > 0.f ? v : 0.f;
                    sH[(mt * 16 + quad * 4 + r) * LD128 + (wave * 2 + j) * 16 + l15] = (bf16)v;
                }
            }
        __syncthreads();

        f32x4 acc2[4][2];
        #pragma unroll
        for (int mt = 0; mt < 4; ++mt)
            #pragma unroll
            for (int j = 0; j < 2; ++j) acc2[mt][j] = (f32x4){0.f, 0.f, 0.f, 0.f};
        #pragma unroll
        for (int mt = 0; mt < 4; ++mt) {
            #pragma unroll
            for (int kt = 0; kt < 4; ++kt) {
                bf16x8 a = *(const bf16x8*)&sH[(mt * 16 + l15) * LD128 + kt * 32 + quad * 8];
                #pragma unroll
                for (int j = 0; j < 2; ++j) acc2[mt][j] = mfma16(a, w2f[j][kt], acc2[mt][j]);
            }
        }
        #pragma unroll
        for (int mt = 0; mt < 4; ++mt) {
            #pragma unroll
            for (int j = 0; j < 2; ++j) {
                const int col = (wave * 2 + j) * 16 + l15;
                const int sel = col >> 6;
                const int c = col & 63;
                #pragma unroll
                for (int r = 0; r < 4; ++r) {
                    int row = mt * 16 + quad * 4 + r;
                    int id = sIdx[row * 2 + sel];
                    if (id >= 0)
                        atomicAdd(&agg[(size_t)id * 64 + c], acc2[mt][j][r] + bias2[j]);
                }
            }
        }
    }
}

// ---------------------------------------------------------------------------
// update: out = relu([emb||agg] @ W1 + b1) @ W2 + b2
// ---------------------------------------------------------------------------
__global__ __launch_bounds__(256) void update_kernel(
    const float* __restrict__ emb, const float* __restrict__ agg,
    const float* __restrict__ W1, const float* __restrict__ b1,  // 128x64, 64
    const float* __restrict__ W2, const float* __restrict__ b2,  // 64x64, 64
    float* __restrict__ out, int N, int numTiles)
{
    __shared__ bf16 sW1t[64 * LD128];  // [n][k], k=128
    __shared__ bf16 sW2t[64 * LD64];   // [n][k], k=64
    __shared__ bf16 sU[64 * LD128];
    __shared__ bf16 sH[64 * LD64];
    __shared__ float sB1[64], sB2[64];

    const int t = threadIdx.x;
    const int wave = t >> 6, lane = t & 63;
    const int l15 = lane & 15, quad = lane >> 4;

    for (int i = t; i < 128 * 64; i += 256) {
        int k = i >> 6, n = i & 63;
        sW1t[n * LD128 + k] = (bf16)W1[i];
    }
    for (int i = t; i < 64 * 64; i += 256) {
        int k = i >> 6, n = i & 63;
        sW2t[n * LD64 + k] = (bf16)W2[i];
    }
    if (t < 64) { sB1[t] = b1[t]; sB2[t] = b2[t]; }

    for (int tile = blockIdx.x; tile < numTiles; tile += gridDim.x) {
        __syncthreads();
        const int base = tile * 64;
        {
            const int r = t >> 2, p = t & 3;
            const int R = base + r;
            if (R < N) {
                const float* srcp = (p < 2) ? (emb + (size_t)R * 64 + p * 32)
                                            : (agg + (size_t)R * 64 + (p - 2) * 32);
                const float4* src = (const float4*)srcp;
                const int cbase = p * 32;
                #pragma unroll
                for (int i = 0; i < 8; ++i) {
                    float4 v = src[i];
                    int c = cbase + i * 4;
                    sU[r * LD128 + c + 0] = (bf16)v.x;
                    sU[r * LD128 + c + 1] = (bf16)v.y;
                    sU[r * LD128 + c + 2] = (bf16)v.z;
                    sU[r * LD128 + c + 3] = (bf16)v.w;
                }
            }
        }
        __syncthreads();

        f32x4 acc[4];
        #pragma unroll
        for (int nt = 0; nt < 4; ++nt) acc[nt] = (f32x4){0.f, 0.f, 0.f, 0.f};
        #pragma unroll
        for (int kt = 0; kt < 4; ++kt) {
            bf16x8 a = *(const bf16x8*)&sU[(wave * 16 + l15) * LD128 + kt * 32 + quad * 8];
            #pragma unroll
            for (int nt = 0; nt < 4; ++nt) {
                bf16x8 bf = *(const bf16x8*)&sW1t[(nt * 16 + l15) * LD128 + kt * 32 + quad * 8];
                acc[nt] = mfma16(a, bf, acc[nt]);
            }
        }
        #pragma unroll
        for (int nt = 0; nt < 4; ++nt) {
            float bias = sB1[nt * 16 + l15];
            #pragma unroll
            for (int r = 0; r < 4; ++r) {
                float v = acc[nt][r] + bias;
                v = v > 0.f ? v : 0.f;
                sH[(wave * 16 + quad * 4 + r) * LD64 + nt * 16 + l15] = (bf16)v;
            }
        }
        __syncthreads();

        f32x4 acc2[4];
        #pragma unroll
        for (int nt = 0; nt < 4; ++nt) acc2[nt] = (f32x4){0.f, 0.f, 0.f, 0.f};
        #pragma unroll
        for (int kt = 0; kt < 2; ++kt) {
            bf16x8 a = *(const bf16x8*)&sH[(wave * 16 + l15) * LD64 + kt * 32 + quad * 8];
            #pragma unroll
            for (int nt = 0; nt < 4; ++nt) {
                bf16x8 bf = *(const bf16x8*)&sW2t[(nt * 16 + l15) * LD64 + kt * 32 + quad * 8];
                acc2[nt] = mfma16(a, bf, acc2[nt]);
            }
        }
        #pragma unroll
        for (int nt = 0; nt < 4; ++nt) {
            float bias = sB2[nt * 16 + l15];
            #pragma unroll
            for (int r = 0; r < 4; ++r) {
                int row = wave * 16 + quad * 4 + r;
                int R = base + row;
                if (R < N)
                    out[(size_t)R * 64 + nt * 16 + l15] = acc2[nt][r] + bias;
            }
        }
    }
}

extern "C" void kernel_launch(void* const* d_in, const int* in_sizes, int n_in,
                              void* d_out, int out_size, void* d_ws, size_t ws_size,
                              hipStream_t stream) {
    const float* emb    = (const float*)d_in[0];
    const int*   rel1   = (const int*)d_in[1];
    const int*   rel2   = (const int*)d_in[2];
    const float* m1W1   = (const float*)d_in[3];
    const float* m1b1   = (const float*)d_in[4];
    const float* m1W2   = (const float*)d_in[5];
    const float* m1b2   = (const float*)d_in[6];
    const float* m2W1   = (const float*)d_in[7];
    const float* m2b1   = (const float*)d_in[8];
    const float* m2W2   = (const float*)d_in[9];
    const float* m2b2   = (const float*)d_in[10];
    const float* uW1    = (const float*)d_in[11];
    const float* ub1    = (const float*)d_in[12];
    const float* uW2    = (const float*)d_in[13];
    const float* ub2    = (const float*)d_in[14];

    const int N  = in_sizes[0] / 64;   // 100000
    const int M1 = in_sizes[1];        // 500000
    const int M2 = in_sizes[2] / 2;    // 1000000
    const int S2 = 2 * M2;             // 2M arg-slots
    const int SCAN_BLOCKS = (N + 2047) / 2048;  // 49

    // workspace layout (256B-aligned)
    char* ws = (char*)d_ws;
    size_t off = 0;
    auto alloc = [&](size_t bytes) -> char* {
        char* p = ws + off;
        off += (bytes + 255) & ~(size_t)255;
        return p;
    };
    float* agg   = (float*)alloc((size_t)N * 64 * sizeof(float));   // 25.6 MB
    // cnt1+cnt2 as ONE contiguous block so a single memset covers both exactly
    int*   cnt1  = (int*)  alloc(2 * (size_t)N * sizeof(int));
    int*   cnt2  = cnt1 + N;
    int*   pos2  = (int*)  alloc((size_t)N * sizeof(int));
    int*   bsum  = (int*)  alloc((size_t)SCAN_BLOCKS * sizeof(int));
    int*   list2 = (int*)  alloc((size_t)S2 * sizeof(int));          // 8 MB
    const size_t needBase = off;
    bf16* embb = (bf16*)alloc((size_t)N * 64 * sizeof(bf16));        // 12.8 MB
    const size_t needBf16 = off;

    const bool sorted  = (ws_size >= needBase);
    const bool bf16emb = (ws_size >= needBf16);

    const int tu = (N + 63) / 64;

    if (sorted) {
        hipMemsetAsync(cnt1, 0, 2 * (size_t)N * sizeof(int), stream);  // cnt1+cnt2
        if (bf16emb) {
            const int n8 = N * 64 / 8;
            convert_kernel<<<3200, 256, 0, stream>>>(emb, embb, n8);
        }
        hist2_kernel<<<2048, 256, 0, stream>>>(rel1, rel2, cnt1, cnt2, M1, S2);
        scanA_kernel<<<SCAN_BLOCKS, 256, 0, stream>>>(cnt2, bsum, N);
        scanB_kernel<<<1, 256, 0, stream>>>(bsum, SCAN_BLOCKS);
        scanC_kernel<<<SCAN_BLOCKS, 256, 0, stream>>>(cnt2, bsum, pos2, N);
        fill_kernel<<<4096, 256, 0, stream>>>(rel2, pos2, list2, S2);
        rel1_dense_kernel<<<tu, 256, 0, stream>>>(emb, cnt1, m1W1, m1b1, m1W2, m1b2,
                                                  agg, N, tu);
        const int t2 = (S2 + 63) / 64;
        const int g2 = t2 < 2048 ? t2 : 2048;
        if (bf16emb)
            rel2_sorted_kernel<true><<<g2, 256, 0, stream>>>(
                emb, embb, rel2, m2W1, m2b1, m2W2, m2b2, list2, agg, S2, t2);
        else
            rel2_sorted_kernel<false><<<g2, 256, 0, stream>>>(
                emb, embb, rel2, m2W1, m2b1, m2W2, m2b2, list2, agg, S2, t2);
    } else {
        hipMemsetAsync(agg, 0, (size_t)N * 64 * sizeof(float), stream);
        const int t1 = (M1 + 63) / 64;
        const int g1 = t1 < 1024 ? t1 : 1024;
        rel1_atomic_kernel<<<g1, 256, 0, stream>>>(emb, rel1, m1W1, m1b1, m1W2, m1b2,
                                                   agg, M1, t1);
        const int t2 = (M2 + 63) / 64;
        const int g2 = t2 < 2048 ? t2 : 2048;
        rel2_atomic_kernel<<<g2, 256, 0, stream>>>(emb, rel2, m2W1, m2b1, m2W2, m2b2,
                                                   agg, M2, t2);
    }

    update_kernel<<<tu, 256, 0, stream>>>(emb, agg, uW1, ub1, uW2, ub2, (float*)d_out, N, tu);
}